// Round 1
// baseline (56.887 us; speedup 1.0000x reference)
//
#include <hip/hip_runtime.h>
#include <math.h>

// EMD1DLoss: out = sqrt( sum_{i,j} (z_s[i]-z_t[j])^2 ) / n
// Algebraic reduction:
//   sum_{i,j}(a_i-b_j)^2 = m*sum(a^2) + n*sum(b^2) - 2*sum(a)*sum(b)
// => four O(n) reductions instead of an O(n*m) pairwise pass.
// n = m = 8192 fp32 -> 64 KB input total. Single block, 1024 threads.

__global__ __launch_bounds__(1024)
void EMD1DLoss_47476568490545_kernel(const float* __restrict__ zs,
                                     const float* __restrict__ zt,
                                     float* __restrict__ out,
                                     int n, int m) {
    const int tid = threadIdx.x;
    float s = 0.f, ss = 0.f, t = 0.f, tt = 0.f;

    // z_s reductions (vectorized float4 + scalar tail)
    const int n4 = n >> 2;
    const float4* zs4 = reinterpret_cast<const float4*>(zs);
    for (int i = tid; i < n4; i += 1024) {
        float4 a = zs4[i];
        s  += (a.x + a.y) + (a.z + a.w);
        ss += (a.x * a.x + a.y * a.y) + (a.z * a.z + a.w * a.w);
    }
    for (int i = (n4 << 2) + tid; i < n; i += 1024) {
        float a = zs[i];
        s += a; ss += a * a;
    }

    // z_t reductions
    const int m4 = m >> 2;
    const float4* zt4 = reinterpret_cast<const float4*>(zt);
    for (int i = tid; i < m4; i += 1024) {
        float4 b = zt4[i];
        t  += (b.x + b.y) + (b.z + b.w);
        tt += (b.x * b.x + b.y * b.y) + (b.z * b.z + b.w * b.w);
    }
    for (int i = (m4 << 2) + tid; i < m; i += 1024) {
        float b = zt[i];
        t += b; tt += b * b;
    }

    // wave (64-lane) shuffle reduction
    #pragma unroll
    for (int off = 32; off > 0; off >>= 1) {
        s  += __shfl_down(s,  off, 64);
        ss += __shfl_down(ss, off, 64);
        t  += __shfl_down(t,  off, 64);
        tt += __shfl_down(tt, off, 64);
    }

    // cross-wave reduction via LDS (16 waves)
    __shared__ float sh[4][16];
    const int wave = tid >> 6;
    const int lane = tid & 63;
    if (lane == 0) {
        sh[0][wave] = s;
        sh[1][wave] = ss;
        sh[2][wave] = t;
        sh[3][wave] = tt;
    }
    __syncthreads();

    if (tid == 0) {
        double S = 0.0, SS = 0.0, T = 0.0, TT = 0.0;
        #pragma unroll
        for (int w = 0; w < 16; ++w) {
            S  += (double)sh[0][w];
            SS += (double)sh[1][w];
            T  += (double)sh[2][w];
            TT += (double)sh[3][w];
        }
        double total = (double)m * SS + (double)n * TT - 2.0 * S * T;
        if (total < 0.0) total = 0.0;  // guard fp cancellation
        out[0] = (float)(sqrt(total) / (double)n);
    }
}

extern "C" void kernel_launch(void* const* d_in, const int* in_sizes, int n_in,
                              void* d_out, int out_size, void* d_ws, size_t ws_size,
                              hipStream_t stream) {
    const float* zs = (const float*)d_in[0];
    const float* zt = (const float*)d_in[1];
    float* out = (float*)d_out;
    const int n = in_sizes[0];
    const int m = in_sizes[1];
    EMD1DLoss_47476568490545_kernel<<<1, 1024, 0, stream>>>(zs, zt, out, n, m);
}

// Round 2
// 55.480 us; speedup vs baseline: 1.0254x; 1.0254x over previous
//
#include <hip/hip_runtime.h>
#include <math.h>

// EMD1DLoss: out = sqrt( sum_{i,j} (z_s[i]-z_t[j])^2 ) / n
// Algebraic identity:
//   sum_{i,j}(a_i-b_j)^2 = m*sum(a^2) + n*sum(b^2) - 2*sum(a)*sum(b)
// => four O(n) reductions; 64 KB total input. Single block, 1024 threads,
// one dispatch. Measured (R1): total timed path 56.9 us, dominated by the
// harness's 268 MB 0xAA ws-poison fill (39.2 us @ 85% HBM peak) + replay
// overhead; this kernel's own dispatch is below the profiler's top-5
// (< 39 us, est. 2-3 us). Kernel-side work is latency-trivial.

__global__ __launch_bounds__(1024)
void EMD1DLoss_47476568490545_kernel(const float* __restrict__ zs,
                                     const float* __restrict__ zt,
                                     float* __restrict__ out,
                                     int n, int m) {
    const int tid = threadIdx.x;
    float s = 0.f, ss = 0.f, t = 0.f, tt = 0.f;

    const float4* zs4 = reinterpret_cast<const float4*>(zs);
    const float4* zt4 = reinterpret_cast<const float4*>(zt);

    if (n == 8192 && m == 8192) {
        // Fast path: fully unrolled, 4 independent float4 loads issued
        // back-to-back before any use (max MLP, single s_waitcnt group).
        float4 a0 = zs4[tid];
        float4 a1 = zs4[tid + 1024];
        float4 b0 = zt4[tid];
        float4 b1 = zt4[tid + 1024];
        s  = (a0.x + a0.y) + (a0.z + a0.w) + (a1.x + a1.y) + (a1.z + a1.w);
        ss = (a0.x * a0.x + a0.y * a0.y) + (a0.z * a0.z + a0.w * a0.w)
           + (a1.x * a1.x + a1.y * a1.y) + (a1.z * a1.z + a1.w * a1.w);
        t  = (b0.x + b0.y) + (b0.z + b0.w) + (b1.x + b1.y) + (b1.z + b1.w);
        tt = (b0.x * b0.x + b0.y * b0.y) + (b0.z * b0.z + b0.w * b0.w)
           + (b1.x * b1.x + b1.y * b1.y) + (b1.z * b1.z + b1.w * b1.w);
    } else {
        // Generic fallback (any n, m)
        const int n4 = n >> 2;
        for (int i = tid; i < n4; i += 1024) {
            float4 a = zs4[i];
            s  += (a.x + a.y) + (a.z + a.w);
            ss += (a.x * a.x + a.y * a.y) + (a.z * a.z + a.w * a.w);
        }
        for (int i = (n4 << 2) + tid; i < n; i += 1024) {
            float a = zs[i];
            s += a; ss += a * a;
        }
        const int m4 = m >> 2;
        for (int i = tid; i < m4; i += 1024) {
            float4 b = zt4[i];
            t  += (b.x + b.y) + (b.z + b.w);
            tt += (b.x * b.x + b.y * b.y) + (b.z * b.z + b.w * b.w);
        }
        for (int i = (m4 << 2) + tid; i < m; i += 1024) {
            float b = zt[i];
            t += b; tt += b * b;
        }
    }

    // wave (64-lane) butterfly reduction
    #pragma unroll
    for (int off = 32; off > 0; off >>= 1) {
        s  += __shfl_down(s,  off, 64);
        ss += __shfl_down(ss, off, 64);
        t  += __shfl_down(t,  off, 64);
        tt += __shfl_down(tt, off, 64);
    }

    // cross-wave reduction via LDS (16 waves)
    __shared__ float sh[4][16];
    const int wave = tid >> 6;
    const int lane = tid & 63;
    if (lane == 0) {
        sh[0][wave] = s;
        sh[1][wave] = ss;
        sh[2][wave] = t;
        sh[3][wave] = tt;
    }
    __syncthreads();

    if (tid == 0) {
        double S = 0.0, SS = 0.0, T = 0.0, TT = 0.0;
        #pragma unroll
        for (int w = 0; w < 16; ++w) {
            S  += (double)sh[0][w];
            SS += (double)sh[1][w];
            T  += (double)sh[2][w];
            TT += (double)sh[3][w];
        }
        double total = (double)m * SS + (double)n * TT - 2.0 * S * T;
        if (total < 0.0) total = 0.0;  // guard fp cancellation
        out[0] = (float)(sqrt(total) / (double)n);
    }
}

extern "C" void kernel_launch(void* const* d_in, const int* in_sizes, int n_in,
                              void* d_out, int out_size, void* d_ws, size_t ws_size,
                              hipStream_t stream) {
    const float* zs = (const float*)d_in[0];
    const float* zt = (const float*)d_in[1];
    float* out = (float*)d_out;
    const int n = in_sizes[0];
    const int m = in_sizes[1];
    EMD1DLoss_47476568490545_kernel<<<1, 1024, 0, stream>>>(zs, zt, out, n, m);
}